// Round 5
// baseline (1340.447 us; speedup 1.0000x reference)
//
#include <hip/hip_runtime.h>

// RGATConv x2 (N=50000, E=800000, IN=HID=128, R=8) for MI355X/gfx950.
//
// Round-13: fused aggregate kept (no xt), but the per-edge relation switch
// (round-12: 8-way scalar branch per edge -> VALUBusy 50%, 108.8us/graph) is
// replaced by branch-free f32 accumulation in LDS via ds_add_f32
// (unsafeAtomicAdd on shared float, fire-and-forget). y layout: 16 nodes x
// 1028 f32 (stride 4 mod 32 banks -> conflict-free b128 GEMM reads; ds_add
// 4-way = 1.58x, acceptable). GEMM phase packs f32->bf16 with
// v_cvt_pk_bf16_f32 (1 instr / 2 elems). Both graphs merged into ONE
// dispatch (grid = 2*ceil(N/16)). Rest identical to round-12.

typedef unsigned short u16;
typedef __attribute__((ext_vector_type(8))) short short8;
typedef __attribute__((ext_vector_type(4))) float floatx4;
typedef __attribute__((ext_vector_type(4))) float float4v;

__device__ __forceinline__ u16 f2bf(float f) {
  union { float f; unsigned u; } v; v.f = f;
  unsigned r = v.u + 0x7FFFu + ((v.u >> 16) & 1u);  // RNE
  return (u16)(r >> 16);
}
__device__ __forceinline__ float bflo(unsigned v) {
  union { unsigned u; float f; } c; c.u = v << 16; return c.f;
}
__device__ __forceinline__ float bfhi(unsigned v) {
  union { unsigned u; float f; } c; c.u = v & 0xffff0000u; return c.f;
}

// ---- 1. pack stacked W into fragment order (per graph) ----------------------
// Wb[(kkg*8 + nt)*512 + lane*8 + j] = W[kkg*32 + (lane>>4)*8 + j][nt*16 + (lane&15)]
// over the stacked [R*128][128] weight (kkg = global K/32 index, 0..31).
// Valid as A-fragment of W^T for the K=1024 GEMM (rows = out-ch).
__global__ void k_prep_wb(const float* __restrict__ W1, const float* __restrict__ W2,
                          u16* __restrict__ Wb, int KK) {
  int t = blockIdx.x * 256 + threadIdx.x;
  int lane = t & 63, nt = (t >> 6) & 7, kk = t >> 9;
  if (kk >= KK) return;
  const float* W = blockIdx.y ? W2 : W1;
  u16* out = Wb + (size_t)blockIdx.y * KK * 4096;
  int q = lane >> 4, m16 = lane & 15;
  int c = nt * 16 + m16;
  short8 v;
#pragma unroll
  for (int j = 0; j < 8; ++j) {
    int k = kk * 32 + q * 8 + j;
    v[j] = (short)f2bf(W[(size_t)k * 128 + c]);
  }
  *(short8*)(out + (size_t)t * 8) = v;
}

// ---- 2. Wq[g][r][d] = sum_c W[r][d][c]*q[c]; Wk likewise --------------------
__global__ void k_prep_wqk(const float* __restrict__ W1, const float* __restrict__ q1,
                           const float* __restrict__ k1, const float* __restrict__ W2,
                           const float* __restrict__ q2, const float* __restrict__ k2,
                           float* __restrict__ Wq, float* __restrict__ Wk, int RD) {
  int wid = (blockIdx.x * 256 + threadIdx.x) >> 6;
  int lane = threadIdx.x & 63;
  if (wid >= 2 * RD) return;
  int g = wid >= RD;
  const float* W = g ? W2 : W1;
  const float* qv = g ? q2 : q1;
  const float* kv = g ? k2 : k1;
  const float* row = W + (size_t)(wid - g * RD) * 128;
  float a0 = row[lane], a1 = row[lane + 64];
  float vq = a0 * qv[lane] + a1 * qv[lane + 64];
  float vk = a0 * kv[lane] + a1 * kv[lane + 64];
#pragma unroll
  for (int off = 32; off; off >>= 1) {
    vq += __shfl_xor(vq, off);
    vk += __shfl_xor(vk, off);
  }
  if (lane == 0) { Wq[wid] = vq; Wk[wid] = vk; }
}

// ---- 3. Bqk[g][kk][lane][j]: fragment of [Wq|Wk] (16 rows/cols) -------------
__global__ void k_prep_bqk(const float* __restrict__ Wq, const float* __restrict__ Wk,
                           u16* __restrict__ Bqk, int R) {
  int total = 2 * 4 * 64 * 8;
  for (int idx = threadIdx.x; idx < total; idx += 256) {
    int j = idx & 7, lane = (idx >> 3) & 63, kk = (idx >> 9) & 3, g = idx >> 11;
    int k = kk * 32 + ((lane >> 4) & 3) * 8 + j;
    int n = lane & 15;
    float v = (n < 8) ? Wq[(g * R + n) * 128 + k] : Wk[(g * R + (n & 7)) * 128 + k];
    Bqk[idx] = f2bf(v);
  }
}

// ---- 4. [sq|sk] = x @ [Wq|Wk] via MFMA; also emit xbf = bf16(x) -------------
__global__ void __launch_bounds__(256) k_sqk(
    const float* __restrict__ x1, const float* __restrict__ x2,
    const u16* __restrict__ Bqk, u16* __restrict__ xbf,
    float* __restrict__ sq, float* __restrict__ sk, int N) {
  int g = blockIdx.y;
  const float* x = g ? x2 : x1;
  u16* xb = xbf + (size_t)g * N * 128;
  int wave = threadIdx.x >> 6, lane = threadIdx.x & 63;
  int m0 = blockIdx.x * 64 + wave * 16;
  int q = lane >> 4, m16 = lane & 15;
  int node = m0 + m16;
  int srow = (node < N) ? node : N - 1;
  short8 bfrag[4];
#pragma unroll
  for (int kk = 0; kk < 4; ++kk) {
    const float* ap = x + (size_t)srow * 128 + kk * 32 + q * 8;
    float4v f0 = *(const float4v*)ap;
    float4v f1 = *(const float4v*)(ap + 4);
    short8 a;
    a[0] = (short)f2bf(f0.x); a[1] = (short)f2bf(f0.y);
    a[2] = (short)f2bf(f0.z); a[3] = (short)f2bf(f0.w);
    a[4] = (short)f2bf(f1.x); a[5] = (short)f2bf(f1.y);
    a[6] = (short)f2bf(f1.z); a[7] = (short)f2bf(f1.w);
    bfrag[kk] = a;
  }
  if (node < N) {
#pragma unroll
    for (int kk = 0; kk < 4; ++kk)
      *(short8*)(xb + (size_t)node * 128 + kk * 32 + q * 8) = bfrag[kk];
  }
  floatx4 accq = (floatx4){0.f, 0.f, 0.f, 0.f};
#pragma unroll
  for (int kk = 0; kk < 4; ++kk) {
    short8 aq = *(const short8*)(Bqk + ((size_t)g * 4 + kk) * 512 + lane * 8);
    accq = __builtin_amdgcn_mfma_f32_16x16x32_bf16(aq, bfrag[kk], accq, 0, 0, 0);
  }
  if (node < N) {
    float* dst = (q < 2 ? sq : sk) + (size_t)(g * N + node) * 8 + (q & 1) * 4;
    *(float4v*)dst = (float4v){accq[0], accq[1], accq[2], accq[3]};
  }
}

// ---- 5a. bucket-level counts (LDS hist per block) ---------------------------
__global__ void __launch_bounds__(256) k_count(
    const int* __restrict__ d1, const int* __restrict__ d2,
    int* __restrict__ gcnt, int N, int E, int NB) {
  __shared__ int h[512];
  int tid = threadIdx.x;
  for (int i = tid; i < NB; i += 256) h[i] = 0;
  __syncthreads();
  int E2 = 2 * E;
  int e0 = blockIdx.x * 4096;
#pragma unroll
  for (int j = 0; j < 16; ++j) {
    int e = e0 + j * 256 + tid;
    if (e < E2) {
      int g = e >= E;
      int d = g ? d2[e - E] : d1[e];
      atomicAdd(&h[(g * N + d) >> 8], 1);
    }
  }
  __syncthreads();
  for (int i = tid; i < NB; i += 256)
    if (h[i]) atomicAdd(&gcnt[i], h[i]);
}

// ---- 5b. scan bucket totals -> bbase/bcur; offs[N2]=total -------------------
__global__ void k_bucket_scan(const int* __restrict__ gcnt, int* __restrict__ bbase,
                              int* __restrict__ bcur, int* __restrict__ offs,
                              int NB, int total, int N2) {
  __shared__ int sd[512];
  int tid = threadIdx.x;
  int v0 = (tid < NB) ? gcnt[tid] : 0;
  int v1 = (tid + 256 < NB) ? gcnt[tid + 256] : 0;
  sd[tid] = v0; sd[tid + 256] = v1;
  __syncthreads();
  for (int off = 1; off < 512; off <<= 1) {
    int t0 = (tid >= off) ? sd[tid - off] : 0;
    int t1 = (tid + 256 >= off) ? sd[tid + 256 - off] : 0;
    __syncthreads();
    sd[tid] += t0; sd[tid + 256] += t1;
    __syncthreads();
  }
  if (tid < NB) { int b = sd[tid] - v0; bbase[tid] = b; bcur[tid] = b; }
  if (tid + 256 < NB) { int b = sd[tid + 256] - v1; bbase[tid + 256] = b; bcur[tid + 256] = b; }
  if (tid == 0) { bbase[NB] = total; offs[N2] = total; }
}

// ---- 5c. bin edges into 256-node buckets (counting-sort per 4096-edge chunk)
__global__ void __launch_bounds__(256) k_bin(
    const int* __restrict__ ei1, const int* __restrict__ et1,
    const int* __restrict__ ei2, const int* __restrict__ et2,
    int* __restrict__ bcur, uint2* __restrict__ staged, int N, int E, int NB) {
  __shared__ int hist[512];
  __shared__ int basev[512];
  __shared__ int runstart[512];
  __shared__ unsigned sta[4096 * 2];  // 32 KB staging (dstg, srcet)
  int tid = threadIdx.x;
  int E2 = 2 * E;
  int e0 = blockIdx.x * 4096;
  int cnt2 = min(4096, E2 - e0);
  for (int i = tid; i < 512; i += 256) hist[i] = 0;
  __syncthreads();
  int dstg[16], srcet[16], rank[16];
#pragma unroll
  for (int j = 0; j < 16; ++j) {
    int e = e0 + j * 256 + tid;
    dstg[j] = -1;
    if (e < E2) {
      int g = e >= E;
      int el = e - (g ? E : 0);
      const int* ei = g ? ei2 : ei1;
      int s = ei[el], d = ei[E + el];
      int etv = (g ? et2 : et1)[el];
      dstg[j] = g * N + d;
      srcet[j] = (s << 3) | etv;
      rank[j] = atomicAdd(&hist[dstg[j] >> 8], 1);
    }
  }
  __syncthreads();
  basev[tid] = hist[tid];
  basev[tid + 256] = hist[tid + 256];
  __syncthreads();
  for (int off = 1; off < 512; off <<= 1) {
    int i0 = tid, i1 = tid + 256;
    int v0 = (i0 >= off) ? basev[i0 - off] : 0;
    int v1 = (i1 >= off) ? basev[i1 - off] : 0;
    __syncthreads();
    basev[i0] += v0; basev[i1] += v1;
    __syncthreads();
  }
  for (int i = tid; i < NB; i += 256)
    if (hist[i] > 0) runstart[i] = atomicAdd(&bcur[i], hist[i]);
  __syncthreads();
#pragma unroll
  for (int j = 0; j < 16; ++j)
    if (dstg[j] >= 0) {
      int b = dstg[j] >> 8;
      int slot = basev[b] - hist[b] + rank[j];
      sta[slot * 2] = (unsigned)dstg[j];
      sta[slot * 2 + 1] = (unsigned)srcet[j];
    }
  __syncthreads();
  for (int i = tid; i < cnt2; i += 256) {
    unsigned dg = sta[i * 2], se = sta[i * 2 + 1];
    int b = (int)(dg >> 8);
    int dest = runstart[b] + (i - (basev[b] - hist[b]));
    staged[dest] = make_uint2(dg, se);
  }
}

// ---- 5d. per-bucket: node-level offs + final sorted csr ---------------------
__global__ void __launch_bounds__(256) k_scatter2(
    const uint2* __restrict__ staged, const int* __restrict__ bbase,
    int* __restrict__ offs, int* __restrict__ csr, int N2) {
  __shared__ int hist[256];
  __shared__ int sd[256];
  __shared__ int cur[256];
  int b = blockIdx.x, tid = threadIdx.x;
  int nb0 = b << 8;
  int nnode = min(256, N2 - nb0);
  int s0 = bbase[b], s1 = bbase[b + 1];
  hist[tid] = 0;
  __syncthreads();
  for (int i = s0 + tid; i < s1; i += 256)
    atomicAdd(&hist[(int)staged[i].x - nb0], 1);
  __syncthreads();
  int v = hist[tid];
  sd[tid] = v; __syncthreads();
  for (int off = 1; off < 256; off <<= 1) {
    int t = (tid >= off) ? sd[tid - off] : 0;
    __syncthreads();
    sd[tid] += t;
    __syncthreads();
  }
  int ex = sd[tid] - v;  // exclusive scan
  if (tid < nnode) offs[nb0 + tid] = s0 + ex;
  cur[tid] = ex;
  __syncthreads();
  for (int i = s0 + tid; i < s1; i += 256) {
    uint2 en = staged[i];
    int node = (int)en.x - nb0;
    int sl = atomicAdd(&cur[node], 1);
    csr[s0 + sl] = (int)en.y;
  }
}

// ---- 6. fused aggregate: softmax + LDS-f32 y accumulate + K=1024 GEMM -------
// One dispatch covers BOTH graphs: g = blockIdx.x >= nbg.
// Phase A (per wave, 4 nodes serial): softmax over incoming edges; weight
// pass does BRANCH-FREE accumulation y[node][rel*128+ch] += w*x via
// ds_add_f32 (unsafeAtomicAdd on LDS f32; address arithmetic on rel).
// Node stride 1028 f32 (bank 4 mod 32) -> conflict-free b128 GEMM reads.
// Phase B: out = ycat @ Wcat, K=1024 MFMA; y read as f32, packed to bf16
// with v_cvt_pk_bf16_f32. D: lane holds out[node=lane&15][ch=nt*16+q*4+reg].
__global__ void __launch_bounds__(256) k_aggregate(
    const int* __restrict__ csr, const int* __restrict__ offs,
    const float* __restrict__ sq, const float* __restrict__ sk,
    const u16* __restrict__ xbf, const u16* __restrict__ Wb,
    const float* __restrict__ b1, const float* __restrict__ b2,
    float* __restrict__ out, int N, int nbg, int KK) {
  __shared__ __align__(16) float ylds[16 * 1028];  // 64.25 KB
  int wave = threadIdx.x >> 6, lane = threadIdx.x & 63;
  int q = lane >> 4, m16 = lane & 15;
  int g = blockIdx.x >= nbg;
  int bl = blockIdx.x - (g ? nbg : 0);
  size_t gN = (size_t)g * N;
  const char* xbfb = (const char*)xbf;

  // zero y
  float4v z4 = (float4v){0.f, 0.f, 0.f, 0.f};
  for (int i = threadIdx.x; i < 16 * 1028 / 4; i += 256)
    *(float4v*)&ylds[i * 4] = z4;
  __syncthreads();

  for (int t = 0; t < 4; ++t) {
    int nl = bl * 16 + wave * 4 + t;
    if (nl >= N) continue;
    int gnode = (int)gN + nl;
    int start = offs[gnode], end = offs[gnode + 1];
    const float* sqn = sq + (size_t)gnode * 8;
    float* yrow = ylds + (wave * 4 + t) * 1028;

    float al[8]; int pl[8];
    float m = -INFINITY;
    {
      int c = 0;
      for (int i = start + lane; i < end; i += 64, ++c) {
        int p = csr[i]; int s = p >> 3, e = p & 7;
        float a = sqn[e] + sk[(gN + s) * 8 + e];
        a = (a > 0.f) ? a : 0.2f * a;
        if (c < 8) { al[c] = a; pl[c] = p; }
        m = fmaxf(m, a);
      }
    }
#pragma unroll
    for (int off = 32; off; off >>= 1) m = fmaxf(m, __shfl_xor(m, off));

    float ssum = 0.f;
    {
      int c = 0;
      for (int i = start + lane; i < end; i += 64, ++c) {
        float a;
        if (c < 8) a = al[c];
        else {
          int p = csr[i]; int s = p >> 3, e = p & 7;
          a = sqn[e] + sk[(gN + s) * 8 + e];
          a = (a > 0.f) ? a : 0.2f * a;
        }
        ssum += __expf(a - m);
      }
    }
#pragma unroll
    for (int off = 32; off; off >>= 1) ssum += __shfl_xor(ssum, off);
    float inv = 1.f / (ssum + 1e-16f);

    int c = 0;
    for (int base = start; base < end; base += 64, ++c) {
      int cnt = min(64, end - base);
      float w = 0.f; int p = 0;
      {
        int i = base + lane;
        if (i < end) {
          float a;
          if (c < 8) { p = pl[c]; a = al[c]; }
          else {
            p = csr[i]; int s = p >> 3, e = p & 7;
            a = sqn[e] + sk[(gN + s) * 8 + e];
            a = (a > 0.f) ? a : 0.2f * a;
          }
          w = __expf(a - m) * inv;
        }
      }
      int j = 0;
      for (; j + 3 < cnt; j += 4) {
        float w0 = __shfl(w, j), w1 = __shfl(w, j + 1),
              w2 = __shfl(w, j + 2), w3 = __shfl(w, j + 3);
        int p0 = __shfl(p, j), p1 = __shfl(p, j + 1),
            p2 = __shfl(p, j + 2), p3 = __shfl(p, j + 3);
        unsigned v0 = *(const unsigned*)(xbfb + ((gN + (unsigned)(p0 >> 3)) << 8) + lane * 4);
        unsigned v1 = *(const unsigned*)(xbfb + ((gN + (unsigned)(p1 >> 3)) << 8) + lane * 4);
        unsigned v2 = *(const unsigned*)(xbfb + ((gN + (unsigned)(p2 >> 3)) << 8) + lane * 4);
        unsigned v3 = *(const unsigned*)(xbfb + ((gN + (unsigned)(p3 >> 3)) << 8) + lane * 4);
        float* a0 = yrow + (p0 & 7) * 128 + lane * 2;
        float* a1 = yrow + (p1 & 7) * 128 + lane * 2;
        float* a2 = yrow + (p2 & 7) * 128 + lane * 2;
        float* a3 = yrow + (p3 & 7) * 128 + lane * 2;
        unsafeAtomicAdd(a0, w0 * bflo(v0)); unsafeAtomicAdd(a0 + 1, w0 * bfhi(v0));
        unsafeAtomicAdd(a1, w1 * bflo(v1)); unsafeAtomicAdd(a1 + 1, w1 * bfhi(v1));
        unsafeAtomicAdd(a2, w2 * bflo(v2)); unsafeAtomicAdd(a2 + 1, w2 * bfhi(v2));
        unsafeAtomicAdd(a3, w3 * bflo(v3)); unsafeAtomicAdd(a3 + 1, w3 * bfhi(v3));
      }
      for (; j < cnt; ++j) {
        float w0 = __shfl(w, j);
        int p0 = __shfl(p, j);
        unsigned v0 = *(const unsigned*)(xbfb + ((gN + (unsigned)(p0 >> 3)) << 8) + lane * 4);
        float* a0 = yrow + (p0 & 7) * 128 + lane * 2;
        unsafeAtomicAdd(a0, w0 * bflo(v0)); unsafeAtomicAdd(a0 + 1, w0 * bfhi(v0));
      }
    }
  }
  __syncthreads();

  // GEMM: wave handles out-ch tiles nt = {2*wave, 2*wave+1}, K = 1024
  const u16* Wbg = Wb + (size_t)g * KK * 4096;
  floatx4 acc0 = (floatx4){0.f, 0.f, 0.f, 0.f};
  floatx4 acc1 = (floatx4){0.f, 0.f, 0.f, 0.f};
  int nt0 = wave * 2, nt1 = wave * 2 + 1;
  const float* brow = ylds + m16 * 1028;
#pragma unroll
  for (int kk = 0; kk < 32; ++kk) {
    float4v f0 = *(const float4v*)(brow + kk * 32 + q * 8);
    float4v f1 = *(const float4v*)(brow + kk * 32 + q * 8 + 4);
    unsigned r0, r1, r2, r3;
    asm("v_cvt_pk_bf16_f32 %0, %1, %2" : "=v"(r0) : "v"(f0.x), "v"(f0.y));
    asm("v_cvt_pk_bf16_f32 %0, %1, %2" : "=v"(r1) : "v"(f0.z), "v"(f0.w));
    asm("v_cvt_pk_bf16_f32 %0, %1, %2" : "=v"(r2) : "v"(f1.x), "v"(f1.y));
    asm("v_cvt_pk_bf16_f32 %0, %1, %2" : "=v"(r3) : "v"(f1.z), "v"(f1.w));
    union { unsigned u[4]; short8 s; } bb;
    bb.u[0] = r0; bb.u[1] = r1; bb.u[2] = r2; bb.u[3] = r3;
    short8 a0 = *(const short8*)(Wbg + ((size_t)(kk * 8 + nt0)) * 512 + lane * 8);
    short8 a1 = *(const short8*)(Wbg + ((size_t)(kk * 8 + nt1)) * 512 + lane * 8);
    acc0 = __builtin_amdgcn_mfma_f32_16x16x32_bf16(a0, bb.s, acc0, 0, 0, 0);
    acc1 = __builtin_amdgcn_mfma_f32_16x16x32_bf16(a1, bb.s, acc1, 0, 0, 0);
  }
  int ln = bl * 16 + m16;
  if (ln < N) {
    const float* bias = g ? b2 : b1;
    float* op = out + (gN + ln) * 128;
    int ch0 = nt0 * 16 + q * 4, ch1 = nt1 * 16 + q * 4;
    float4v bv0 = *(const float4v*)(bias + ch0);
    float4v bv1 = *(const float4v*)(bias + ch1);
    float4v o0 = (float4v){fmaxf(acc0[0] + bv0.x, 0.f), fmaxf(acc0[1] + bv0.y, 0.f),
                           fmaxf(acc0[2] + bv0.z, 0.f), fmaxf(acc0[3] + bv0.w, 0.f)};
    float4v o1 = (float4v){fmaxf(acc1[0] + bv1.x, 0.f), fmaxf(acc1[1] + bv1.y, 0.f),
                           fmaxf(acc1[2] + bv1.z, 0.f), fmaxf(acc1[3] + bv1.w, 0.f)};
    *(float4v*)(op + ch0) = o0;
    *(float4v*)(op + ch1) = o1;
  }
}

// -----------------------------------------------------------------------------
extern "C" void kernel_launch(void* const* d_in, const int* in_sizes, int n_in,
                              void* d_out, int out_size, void* d_ws, size_t ws_size,
                              hipStream_t stream) {
  const float* x1 = (const float*)d_in[0];
  const int* ei1 = (const int*)d_in[1];
  const int* et1 = (const int*)d_in[2];
  const float* x2 = (const float*)d_in[3];
  const int* ei2 = (const int*)d_in[4];
  const int* et2 = (const int*)d_in[5];
  const float* W1 = (const float*)d_in[6];
  const float* q1 = (const float*)d_in[7];
  const float* k1 = (const float*)d_in[8];
  const float* b1 = (const float*)d_in[9];
  const float* W2 = (const float*)d_in[10];
  const float* q2 = (const float*)d_in[11];
  const float* k2 = (const float*)d_in[12];
  const float* b2 = (const float*)d_in[13];

  const int N = in_sizes[0] / 128;
  const int E = in_sizes[1] / 2;
  const int R = in_sizes[6] / (128 * 128);
  const int KK = R * 4;
  const int N2 = 2 * N;
  const int NB = (N2 + 255) >> 8;           // 256-node buckets (<=512)

  size_t off = 0;
  char* w = (char*)d_ws;
  auto carve = [&](size_t bytes) -> void* {
    void* p = w + off;
    off += (bytes + 255) & ~(size_t)255;
    return p;
  };
  u16* Wb = (u16*)carve((size_t)2 * KK * 4096 * 2);
  u16* Bqk = (u16*)carve((size_t)2 * 4 * 64 * 8 * 2);
  float* Wq = (float*)carve((size_t)2 * R * 128 * 4);
  float* Wk = (float*)carve((size_t)2 * R * 128 * 4);
  u16* xbf = (u16*)carve((size_t)N2 * 128 * 2);         // 25.6MB, both graphs
  float* sq = (float*)carve((size_t)N2 * 8 * 4);
  float* sk = (float*)carve((size_t)N2 * 8 * 4);
  int* offs = (int*)carve((size_t)(N2 + 1) * 4);
  int* gcnt = (int*)carve(512 * 4);
  int* bbase = (int*)carve(520 * 4);
  int* bcur = (int*)carve(512 * 4);
  uint2* staged = (uint2*)carve((size_t)2 * E * 8);
  int* csr = (int*)carve((size_t)2 * E * 4);
  if (off > ws_size) return;

  const int nbin = (2 * E + 4095) / 4096;
  const int nbg = (N + 15) / 16;

  hipMemsetAsync(gcnt, 0, 512 * 4, stream);
  k_prep_wb<<<dim3((KK * 512 + 255) / 256, 2), dim3(256), 0, stream>>>(W1, W2, Wb, KK);
  k_prep_wqk<<<dim3((2 * R * 128 * 64 + 255) / 256), dim3(256), 0, stream>>>(
      W1, q1, k1, W2, q2, k2, Wq, Wk, R * 128);
  k_prep_bqk<<<dim3(1), dim3(256), 0, stream>>>(Wq, Wk, Bqk, R);
  k_sqk<<<dim3((N + 63) / 64, 2), dim3(256), 0, stream>>>(x1, x2, Bqk, xbf, sq, sk, N);
  k_count<<<dim3(nbin), dim3(256), 0, stream>>>(ei1 + E, ei2 + E, gcnt, N, E, NB);
  k_bucket_scan<<<dim3(1), dim3(256), 0, stream>>>(gcnt, bbase, bcur, offs, NB, 2 * E, N2);
  k_bin<<<dim3(nbin), dim3(256), 0, stream>>>(ei1, et1, ei2, et2, bcur, staged, N, E, NB);
  k_scatter2<<<dim3(NB), dim3(256), 0, stream>>>(staged, bbase, offs, csr, N2);

  k_aggregate<<<dim3(2 * nbg), dim3(256), 0, stream>>>(
      csr, offs, sq, sk, xbf, Wb, b1, b2, (float*)d_out, N, nbg, KK);
}

// Round 6
// 489.634 us; speedup vs baseline: 2.7377x; 2.7377x over previous
//
#include <hip/hip_runtime.h>

// RGATConv x2 (N=50000, E=800000, IN=HID=128, R=8) for MI355X/gfx950.
//
// Round-14: REVERT gemm_xt/aggregate to round-11 (verified 356us) and replace
// the 2-phase bucket sort (k_bin + k_scatter2, 12.8MB staged intermediate,
// ~half of a measured 165us non-aggregate remainder) with direct atomic
// placement: per-node degree count (global atomics) -> 3 tiny scans ->
// csr[atomicAdd(cur[dst])] = srcet. Aggregate never needed within-node order.
// Round-13 lesson: unsafeAtomicAdd on a pointer into __shared__ compiles to
// FLAT atomics (10x regression) — no per-edge atomics on the critical path.

typedef unsigned short u16;
typedef __attribute__((ext_vector_type(8))) short short8;
typedef __attribute__((ext_vector_type(4))) float floatx4;
typedef __attribute__((ext_vector_type(4))) float float4v;
typedef __attribute__((ext_vector_type(4))) unsigned uint4v;

__device__ __forceinline__ u16 f2bf(float f) {
  union { float f; unsigned u; } v; v.f = f;
  unsigned r = v.u + 0x7FFFu + ((v.u >> 16) & 1u);  // RNE
  return (u16)(r >> 16);
}
__device__ __forceinline__ float bflo(unsigned v) {
  union { unsigned u; float f; } c; c.u = v << 16; return c.f;
}
__device__ __forceinline__ float bfhi(unsigned v) {
  union { unsigned u; float f; } c; c.u = v & 0xffff0000u; return c.f;
}

// ---- 1. pack stacked W into fragment order (per graph) ----------------------
__global__ void k_prep_wb(const float* __restrict__ W1, const float* __restrict__ W2,
                          u16* __restrict__ Wb, int KK) {
  int t = blockIdx.x * 256 + threadIdx.x;
  int lane = t & 63, nt = (t >> 6) & 7, kk = t >> 9;
  if (kk >= KK) return;
  const float* W = blockIdx.y ? W2 : W1;
  u16* out = Wb + (size_t)blockIdx.y * KK * 4096;
  int q = lane >> 4, m16 = lane & 15;
  int c = nt * 16 + m16;
  short8 v;
#pragma unroll
  for (int j = 0; j < 8; ++j) {
    int k = kk * 32 + q * 8 + j;
    v[j] = (short)f2bf(W[(size_t)k * 128 + c]);
  }
  *(short8*)(out + (size_t)t * 8) = v;
}

// ---- 2. Wq[g][r][d] = sum_c W[r][d][c]*q[c]; Wk likewise --------------------
__global__ void k_prep_wqk(const float* __restrict__ W1, const float* __restrict__ q1,
                           const float* __restrict__ k1, const float* __restrict__ W2,
                           const float* __restrict__ q2, const float* __restrict__ k2,
                           float* __restrict__ Wq, float* __restrict__ Wk, int RD) {
  int wid = (blockIdx.x * 256 + threadIdx.x) >> 6;
  int lane = threadIdx.x & 63;
  if (wid >= 2 * RD) return;
  int g = wid >= RD;
  const float* W = g ? W2 : W1;
  const float* qv = g ? q2 : q1;
  const float* kv = g ? k2 : k1;
  const float* row = W + (size_t)(wid - g * RD) * 128;
  float a0 = row[lane], a1 = row[lane + 64];
  float vq = a0 * qv[lane] + a1 * qv[lane + 64];
  float vk = a0 * kv[lane] + a1 * kv[lane + 64];
#pragma unroll
  for (int off = 32; off; off >>= 1) {
    vq += __shfl_xor(vq, off);
    vk += __shfl_xor(vk, off);
  }
  if (lane == 0) { Wq[wid] = vq; Wk[wid] = vk; }
}

// ---- 3. Bqk[g][kk][lane][j]: fragment of [Wq|Wk] (16 rows/cols) -------------
__global__ void k_prep_bqk(const float* __restrict__ Wq, const float* __restrict__ Wk,
                           u16* __restrict__ Bqk, int R) {
  int total = 2 * 4 * 64 * 8;
  for (int idx = threadIdx.x; idx < total; idx += 256) {
    int j = idx & 7, lane = (idx >> 3) & 63, kk = (idx >> 9) & 3, g = idx >> 11;
    int k = kk * 32 + ((lane >> 4) & 3) * 8 + j;
    int n = lane & 15;
    float v = (n < 8) ? Wq[(g * R + n) * 128 + k] : Wk[(g * R + (n & 7)) * 128 + k];
    Bqk[idx] = f2bf(v);
  }
}

// ---- 4a. per-node degree count (global atomics) -----------------------------
__global__ void __launch_bounds__(256) k_count(
    const int* __restrict__ d1, const int* __restrict__ d2,
    int* __restrict__ nodecnt, int N, int E) {
  int E2 = 2 * E;
  int e0 = blockIdx.x * 4096;
#pragma unroll
  for (int j = 0; j < 16; ++j) {
    int e = e0 + j * 256 + threadIdx.x;
    if (e < E2) {
      int g = e >= E;
      int d = g ? d2[e - E] : d1[e];
      atomicAdd(&nodecnt[g * N + d], 1);
    }
  }
}

// ---- 4b. per-bucket exclusive scan of 256 node counts -----------------------
__global__ void __launch_bounds__(256) k_scan1(
    const int* __restrict__ nodecnt, int* __restrict__ exls,
    int* __restrict__ bsum, int N2) {
  __shared__ int sd[256];
  int tid = threadIdx.x;
  int n = (blockIdx.x << 8) + tid;
  int v = (n < N2) ? nodecnt[n] : 0;
  sd[tid] = v;
  __syncthreads();
  for (int off = 1; off < 256; off <<= 1) {
    int t = (tid >= off) ? sd[tid - off] : 0;
    __syncthreads();
    sd[tid] += t;
    __syncthreads();
  }
  if (n < N2) exls[n] = sd[tid] - v;
  if (tid == 255) bsum[blockIdx.x] = sd[255];
}

// ---- 4c. scan bucket sums -> bbase; offs[N2] = total ------------------------
__global__ void k_scan2(const int* __restrict__ bsum, int* __restrict__ bbase,
                        int* __restrict__ offs, int NB, int total, int N2) {
  __shared__ int sd[512];
  int tid = threadIdx.x;
  int v0 = (tid < NB) ? bsum[tid] : 0;
  int v1 = (tid + 256 < NB) ? bsum[tid + 256] : 0;
  sd[tid] = v0; sd[tid + 256] = v1;
  __syncthreads();
  for (int off = 1; off < 512; off <<= 1) {
    int t0 = (tid >= off) ? sd[tid - off] : 0;
    int t1 = (tid + 256 >= off) ? sd[tid + 256 - off] : 0;
    __syncthreads();
    sd[tid] += t0; sd[tid + 256] += t1;
    __syncthreads();
  }
  if (tid < NB) bbase[tid] = sd[tid] - v0;
  if (tid + 256 < NB) bbase[tid + 256] = sd[tid + 256] - v1;
  if (tid == 0) { bbase[NB] = total; offs[N2] = total; }
}

// ---- 4d. offs[n] = bbase[bucket] + exls[n]; cur = offs ----------------------
__global__ void __launch_bounds__(256) k_scan3(
    const int* __restrict__ exls, const int* __restrict__ bbase,
    int* __restrict__ offs, int* __restrict__ cur, int N2) {
  int n = (blockIdx.x << 8) + threadIdx.x;
  if (n < N2) {
    int v = bbase[blockIdx.x] + exls[n];
    offs[n] = v;
    cur[n] = v;
  }
}

// ---- 4e. place edges: csr[atomicAdd(cur[dstg])] = (src<<3)|rel --------------
__global__ void __launch_bounds__(256) k_place(
    const int* __restrict__ ei1, const int* __restrict__ et1,
    const int* __restrict__ ei2, const int* __restrict__ et2,
    int* __restrict__ cur, int* __restrict__ csr, int N, int E) {
  int E2 = 2 * E;
  int e0 = blockIdx.x * 4096;
#pragma unroll
  for (int j = 0; j < 16; ++j) {
    int e = e0 + j * 256 + threadIdx.x;
    if (e < E2) {
      int g = e >= E;
      int el = e - (g ? E : 0);
      const int* ei = g ? ei2 : ei1;
      int s = ei[el], d = ei[E + el];
      int etv = (g ? et2 : et1)[el];
      int slot = atomicAdd(&cur[g * N + d], 1);
      csr[slot] = (s << 3) | etv;
    }
  }
}

// ---- 6a. xt[r][n][c] = x_n @ W_r, fused [sq|sk] = x @ [Wq|Wk] ---------------
// (round-11 version: operand swap, XOR-granule swizzle, double-buffered
// wave-private LDS, no barriers; gridDim.y=2 splits relations.)
__global__ void __launch_bounds__(256) k_gemm_xt(
    const float* __restrict__ x, const u16* __restrict__ Wb,
    const u16* __restrict__ Bqk, u16* __restrict__ xt,
    float* __restrict__ sq, float* __restrict__ sk,
    int N, int R, int node_base) {
  __shared__ u16 st[4][2][2048];  // 4 waves x 2 buffers x 4KB
  int wave = threadIdx.x >> 6, lane = threadIdx.x & 63;
  int m0 = blockIdx.x * 64 + wave * 16;
  int rbase = blockIdx.y * 4;
  int q = lane >> 4, m16 = lane & 15;
  int node = m0 + m16;
  int srow = (node < N) ? node : N - 1;
  short8 bfrag[4];
#pragma unroll
  for (int kk = 0; kk < 4; ++kk) {
    const float* ap = x + (size_t)srow * 128 + kk * 32 + q * 8;
    float4v f0 = *(const float4v*)ap;
    float4v f1 = *(const float4v*)(ap + 4);
    short8 a;
    a[0] = (short)f2bf(f0.x); a[1] = (short)f2bf(f0.y);
    a[2] = (short)f2bf(f0.z); a[3] = (short)f2bf(f0.w);
    a[4] = (short)f2bf(f1.x); a[5] = (short)f2bf(f1.y);
    a[6] = (short)f2bf(f1.z); a[7] = (short)f2bf(f1.w);
    bfrag[kk] = a;
  }
  if (blockIdx.y == 0) {
    floatx4 accq = (floatx4){0.f, 0.f, 0.f, 0.f};
#pragma unroll
    for (int kk = 0; kk < 4; ++kk) {
      short8 aq = *(const short8*)(Bqk + (size_t)kk * 512 + lane * 8);
      accq = __builtin_amdgcn_mfma_f32_16x16x32_bf16(aq, bfrag[kk], accq, 0, 0, 0);
    }
    if (node < N) {
      float* dst = (q < 2 ? sq : sk) + (size_t)(node_base + node) * 8 + (q & 1) * 4;
      *(float4v*)dst = (float4v){accq[0], accq[1], accq[2], accq[3]};
    }
  }
#pragma unroll
  for (int rr = 0; rr < 4; ++rr) {
    int r = rbase + rr;
    u16* s = st[wave][rr & 1];
    floatx4 acc[8];
#pragma unroll
    for (int nt = 0; nt < 8; ++nt) acc[nt] = (floatx4){0.f, 0.f, 0.f, 0.f};
#pragma unroll
    for (int kk = 0; kk < 4; ++kk) {
      const u16* wbp = Wb + ((size_t)((r * 4 + kk) * 8) * 64 + lane) * 8;
#pragma unroll
      for (int nt = 0; nt < 8; ++nt) {
        short8 a = *(const short8*)(wbp + nt * 512);
        acc[nt] = __builtin_amdgcn_mfma_f32_16x16x32_bf16(a, bfrag[kk], acc[nt], 0, 0, 0);
      }
    }
#pragma unroll
    for (int nt = 0; nt < 8; ++nt) {
      union { u16 h[4]; unsigned long long u; } pk;
      pk.h[0] = f2bf(acc[nt][0]); pk.h[1] = f2bf(acc[nt][1]);
      pk.h[2] = f2bf(acc[nt][2]); pk.h[3] = f2bf(acc[nt][3]);
      int c16 = 2 * nt + (q >> 1);
      *(unsigned long long*)(s + (((m16 << 4) + (c16 ^ m16)) << 3) + ((q & 1) << 2)) = pk.u;
    }
#pragma unroll
    for (int it = 0; it < 4; ++it) {
      int rl = it * 4 + q;
      int gm = m0 + rl;
      if (gm < N) {
        uint4v vv = *(const uint4v*)(s + (((rl << 4) + (m16 ^ rl)) << 3));
        *(uint4v*)(xt + ((size_t)r * N + gm) * 128 + m16 * 8) = vv;
      }
    }
  }
}

// ---- 6b. per-dst softmax + gather: one wave per node (round-11 version) -----
__global__ void __launch_bounds__(256) k_aggregate(
    const int* __restrict__ csr, const int* __restrict__ offs,
    const float* __restrict__ sq, const float* __restrict__ sk,
    const u16* __restrict__ xt, const float* __restrict__ bias,
    float* __restrict__ out, int N, int node_base) {
  int nl = blockIdx.x * 4 + (threadIdx.x >> 6);
  int lane = threadIdx.x & 63;
  if (nl >= N) return;
  int node = node_base + nl;
  int start = offs[node], end = offs[node + 1];
  const float* sqn = sq + (size_t)node * 8;

  float al[8]; int pl[8];
  float m = -INFINITY;
  {
    int c = 0;
    for (int i = start + lane; i < end; i += 64, ++c) {
      int p = csr[i]; int s = p >> 3, e = p & 7;
      float a = sqn[e] + sk[(size_t)(node_base + s) * 8 + e];
      a = (a > 0.f) ? a : 0.2f * a;
      if (c < 8) { al[c] = a; pl[c] = p; }
      m = fmaxf(m, a);
    }
  }
#pragma unroll
  for (int off = 32; off; off >>= 1) m = fmaxf(m, __shfl_xor(m, off));

  float ssum = 0.f;
  {
    int c = 0;
    for (int i = start + lane; i < end; i += 64, ++c) {
      float a;
      if (c < 8) a = al[c];
      else {
        int p = csr[i]; int s = p >> 3, e = p & 7;
        a = sqn[e] + sk[(size_t)(node_base + s) * 8 + e];
        a = (a > 0.f) ? a : 0.2f * a;
      }
      ssum += __expf(a - m);
    }
  }
#pragma unroll
  for (int off = 32; off; off >>= 1) ssum += __shfl_xor(ssum, off);
  float inv = 1.f / (ssum + 1e-16f);

  float acc0 = 0.f, acc1 = 0.f;
  const char* xtb = (const char*)xt;
  int c = 0;
  for (int base = start; base < end; base += 64, ++c) {
    int cnt = min(64, end - base);
    float w = 0.f; int b = 0;
    {
      int i = base + lane;
      if (i < end) {
        int p; float a;
        if (c < 8) { p = pl[c]; a = al[c]; }
        else {
          p = csr[i]; int s = p >> 3, e = p & 7;
          a = sqn[e] + sk[(size_t)(node_base + s) * 8 + e];
          a = (a > 0.f) ? a : 0.2f * a;
        }
        w = __expf(a - m) * inv;
        b = ((p & 7) * N + (p >> 3)) << 8;  // xt row base in BYTES
      }
    }
    int j = 0;
    for (; j + 3 < cnt; j += 4) {
      float w0 = __shfl(w, j), w1 = __shfl(w, j + 1),
            w2 = __shfl(w, j + 2), w3 = __shfl(w, j + 3);
      int b0 = __shfl(b, j), b1 = __shfl(b, j + 1),
          b2 = __shfl(b, j + 2), b3 = __shfl(b, j + 3);
      unsigned v0 = *(const unsigned*)(xtb + b0 + lane * 4);
      unsigned v1 = *(const unsigned*)(xtb + b1 + lane * 4);
      unsigned v2 = *(const unsigned*)(xtb + b2 + lane * 4);
      unsigned v3 = *(const unsigned*)(xtb + b3 + lane * 4);
      acc0 += w0 * bflo(v0); acc1 += w0 * bfhi(v0);
      acc0 += w1 * bflo(v1); acc1 += w1 * bfhi(v1);
      acc0 += w2 * bflo(v2); acc1 += w2 * bfhi(v2);
      acc0 += w3 * bflo(v3); acc1 += w3 * bfhi(v3);
    }
    for (; j < cnt; ++j) {
      float w0 = __shfl(w, j);
      int b0 = __shfl(b, j);
      unsigned v0 = *(const unsigned*)(xtb + b0 + lane * 4);
      acc0 += w0 * bflo(v0); acc1 += w0 * bfhi(v0);
    }
  }
  float o0 = fmaxf(acc0 + bias[lane * 2], 0.f);
  float o1 = fmaxf(acc1 + bias[lane * 2 + 1], 0.f);
  union { float f[2]; unsigned long long u; } pk;
  pk.f[0] = o0; pk.f[1] = o1;
  __builtin_nontemporal_store(pk.u,
      (unsigned long long*)(out + (size_t)nl * 128 + lane * 2));
}

// -----------------------------------------------------------------------------
extern "C" void kernel_launch(void* const* d_in, const int* in_sizes, int n_in,
                              void* d_out, int out_size, void* d_ws, size_t ws_size,
                              hipStream_t stream) {
  const float* x1 = (const float*)d_in[0];
  const int* ei1 = (const int*)d_in[1];
  const int* et1 = (const int*)d_in[2];
  const float* x2 = (const float*)d_in[3];
  const int* ei2 = (const int*)d_in[4];
  const int* et2 = (const int*)d_in[5];
  const float* W1 = (const float*)d_in[6];
  const float* q1 = (const float*)d_in[7];
  const float* k1 = (const float*)d_in[8];
  const float* b1 = (const float*)d_in[9];
  const float* W2 = (const float*)d_in[10];
  const float* q2 = (const float*)d_in[11];
  const float* k2 = (const float*)d_in[12];
  const float* b2 = (const float*)d_in[13];

  const int N = in_sizes[0] / 128;
  const int E = in_sizes[1] / 2;
  const int R = in_sizes[6] / (128 * 128);
  const int KK = R * 4;
  const int N2 = 2 * N;
  const int NB = (N2 + 255) >> 8;           // 256-node buckets (<=512)

  size_t off = 0;
  char* w = (char*)d_ws;
  auto carve = [&](size_t bytes) -> void* {
    void* p = w + off;
    off += (bytes + 255) & ~(size_t)255;
    return p;
  };
  u16* xt = (u16*)carve((size_t)R * N * 128 * 2);       // per-graph, reused
  u16* Wb = (u16*)carve((size_t)2 * KK * 4096 * 2);
  u16* Bqk = (u16*)carve((size_t)2 * 4 * 64 * 8 * 2);
  float* Wq = (float*)carve((size_t)2 * R * 128 * 4);
  float* Wk = (float*)carve((size_t)2 * R * 128 * 4);
  float* sq = (float*)carve((size_t)N2 * 8 * 4);
  float* sk = (float*)carve((size_t)N2 * 8 * 4);
  int* offs = (int*)carve((size_t)(N2 + 1) * 4);
  int* nodecnt = (int*)carve((size_t)N2 * 4);
  int* exls = (int*)carve((size_t)N2 * 4);
  int* cur = (int*)carve((size_t)N2 * 4);
  int* bsum = (int*)carve(512 * 4);
  int* bbase = (int*)carve(520 * 4);
  int* csr = (int*)carve((size_t)2 * E * 4);
  if (off > ws_size) return;

  const int nbin = (2 * E + 4095) / 4096;

  hipMemsetAsync(nodecnt, 0, (size_t)N2 * 4, stream);
  k_prep_wb<<<dim3((KK * 512 + 255) / 256, 2), dim3(256), 0, stream>>>(W1, W2, Wb, KK);
  k_prep_wqk<<<dim3((2 * R * 128 * 64 + 255) / 256), dim3(256), 0, stream>>>(
      W1, q1, k1, W2, q2, k2, Wq, Wk, R * 128);
  k_prep_bqk<<<dim3(1), dim3(256), 0, stream>>>(Wq, Wk, Bqk, R);
  k_count<<<dim3(nbin), dim3(256), 0, stream>>>(ei1 + E, ei2 + E, nodecnt, N, E);
  k_scan1<<<dim3(NB), dim3(256), 0, stream>>>(nodecnt, exls, bsum, N2);
  k_scan2<<<dim3(1), dim3(256), 0, stream>>>(bsum, bbase, offs, NB, 2 * E, N2);
  k_scan3<<<dim3(NB), dim3(256), 0, stream>>>(exls, bbase, offs, cur, N2);
  k_place<<<dim3(nbin), dim3(256), 0, stream>>>(ei1, et1, ei2, et2, cur, csr, N, E);

  for (int g = 0; g < 2; ++g) {
    const float* x = g ? x2 : x1;
    const float* bv = g ? b2 : b1;
    float* outp = (float*)d_out + (size_t)g * N * 128;
    k_gemm_xt<<<dim3((N + 63) / 64, 2), dim3(256), 0, stream>>>(
        x, Wb + (size_t)g * KK * 4096, Bqk + (size_t)g * 2048, xt,
        sq, sk, N, R, g * N);
    k_aggregate<<<dim3((N + 3) / 4), dim3(256), 0, stream>>>(
        csr, offs, sq, sk, xt, bv, outp, N, g * N);
  }
}

// Round 7
// 360.758 us; speedup vs baseline: 3.7156x; 1.3572x over previous
//
#include <hip/hip_runtime.h>

// RGATConv x2 (N=50000, E=800000, IN=HID=128, R=8) for MI355X/gfx950.
//
// Round-15: full revert to round-11 structure (356us verified) + ONE change:
// k_gemm_xt occupancy. gridDim.y 2->4 (2 relations/block, grid 3128) and
// single 16KB LDS buffer (round-10/11 A/B: dbuf is worthless) -> caps move
// from {grid 6.1, LDS 5} blocks/CU to {grid 12.2, LDS 10}. x re-read is
// L3-absorbed (round-11 FETCH == x read once). Round-14 lesson: random 4B
// global scatter write-amplifies 16x (105MB for 6.4MB csr) — the LDS-staged
// 2-phase bucket sort is the right design; restored verbatim.

typedef unsigned short u16;
typedef __attribute__((ext_vector_type(8))) short short8;
typedef __attribute__((ext_vector_type(4))) float floatx4;
typedef __attribute__((ext_vector_type(4))) float float4v;
typedef __attribute__((ext_vector_type(4))) unsigned uint4v;

__device__ __forceinline__ u16 f2bf(float f) {
  union { float f; unsigned u; } v; v.f = f;
  unsigned r = v.u + 0x7FFFu + ((v.u >> 16) & 1u);  // RNE
  return (u16)(r >> 16);
}
__device__ __forceinline__ float bflo(unsigned v) {
  union { unsigned u; float f; } c; c.u = v << 16; return c.f;
}
__device__ __forceinline__ float bfhi(unsigned v) {
  union { unsigned u; float f; } c; c.u = v & 0xffff0000u; return c.f;
}

// ---- 1. pack stacked W into fragment order (per graph) ----------------------
__global__ void k_prep_wb(const float* __restrict__ W1, const float* __restrict__ W2,
                          u16* __restrict__ Wb, int KK) {
  int t = blockIdx.x * 256 + threadIdx.x;
  int lane = t & 63, nt = (t >> 6) & 7, kk = t >> 9;
  if (kk >= KK) return;
  const float* W = blockIdx.y ? W2 : W1;
  u16* out = Wb + (size_t)blockIdx.y * KK * 4096;
  int q = lane >> 4, m16 = lane & 15;
  int c = nt * 16 + m16;
  short8 v;
#pragma unroll
  for (int j = 0; j < 8; ++j) {
    int k = kk * 32 + q * 8 + j;
    v[j] = (short)f2bf(W[(size_t)k * 128 + c]);
  }
  *(short8*)(out + (size_t)t * 8) = v;
}

// ---- 2. Wq[g][r][d] = sum_c W[r][d][c]*q[c]; Wk likewise --------------------
__global__ void k_prep_wqk(const float* __restrict__ W1, const float* __restrict__ q1,
                           const float* __restrict__ k1, const float* __restrict__ W2,
                           const float* __restrict__ q2, const float* __restrict__ k2,
                           float* __restrict__ Wq, float* __restrict__ Wk, int RD) {
  int wid = (blockIdx.x * 256 + threadIdx.x) >> 6;
  int lane = threadIdx.x & 63;
  if (wid >= 2 * RD) return;
  int g = wid >= RD;
  const float* W = g ? W2 : W1;
  const float* qv = g ? q2 : q1;
  const float* kv = g ? k2 : k1;
  const float* row = W + (size_t)(wid - g * RD) * 128;
  float a0 = row[lane], a1 = row[lane + 64];
  float vq = a0 * qv[lane] + a1 * qv[lane + 64];
  float vk = a0 * kv[lane] + a1 * kv[lane + 64];
#pragma unroll
  for (int off = 32; off; off >>= 1) {
    vq += __shfl_xor(vq, off);
    vk += __shfl_xor(vk, off);
  }
  if (lane == 0) { Wq[wid] = vq; Wk[wid] = vk; }
}

// ---- 3. Bqk[g][kk][lane][j]: fragment of [Wq|Wk] (16 rows/cols) -------------
__global__ void k_prep_bqk(const float* __restrict__ Wq, const float* __restrict__ Wk,
                           u16* __restrict__ Bqk, int R) {
  int total = 2 * 4 * 64 * 8;
  for (int idx = threadIdx.x; idx < total; idx += 256) {
    int j = idx & 7, lane = (idx >> 3) & 63, kk = (idx >> 9) & 3, g = idx >> 11;
    int k = kk * 32 + ((lane >> 4) & 3) * 8 + j;
    int n = lane & 15;
    float v = (n < 8) ? Wq[(g * R + n) * 128 + k] : Wk[(g * R + (n & 7)) * 128 + k];
    Bqk[idx] = f2bf(v);
  }
}

// ---- 5a. bucket-level counts (LDS hist per block) ---------------------------
__global__ void __launch_bounds__(256) k_count(
    const int* __restrict__ d1, const int* __restrict__ d2,
    int* __restrict__ gcnt, int N, int E, int NB) {
  __shared__ int h[512];
  int tid = threadIdx.x;
  for (int i = tid; i < NB; i += 256) h[i] = 0;
  __syncthreads();
  int E2 = 2 * E;
  int e0 = blockIdx.x * 4096;
#pragma unroll
  for (int j = 0; j < 16; ++j) {
    int e = e0 + j * 256 + tid;
    if (e < E2) {
      int g = e >= E;
      int d = g ? d2[e - E] : d1[e];
      atomicAdd(&h[(g * N + d) >> 8], 1);
    }
  }
  __syncthreads();
  for (int i = tid; i < NB; i += 256)
    if (h[i]) atomicAdd(&gcnt[i], h[i]);
}

// ---- 5b. scan bucket totals -> bbase/bcur; offs[N2]=total -------------------
__global__ void k_bucket_scan(const int* __restrict__ gcnt, int* __restrict__ bbase,
                              int* __restrict__ bcur, int* __restrict__ offs,
                              int NB, int total, int N2) {
  __shared__ int sd[512];
  int tid = threadIdx.x;
  int v0 = (tid < NB) ? gcnt[tid] : 0;
  int v1 = (tid + 256 < NB) ? gcnt[tid + 256] : 0;
  sd[tid] = v0; sd[tid + 256] = v1;
  __syncthreads();
  for (int off = 1; off < 512; off <<= 1) {
    int t0 = (tid >= off) ? sd[tid - off] : 0;
    int t1 = (tid + 256 >= off) ? sd[tid + 256 - off] : 0;
    __syncthreads();
    sd[tid] += t0; sd[tid + 256] += t1;
    __syncthreads();
  }
  if (tid < NB) { int b = sd[tid] - v0; bbase[tid] = b; bcur[tid] = b; }
  if (tid + 256 < NB) { int b = sd[tid + 256] - v1; bbase[tid + 256] = b; bcur[tid + 256] = b; }
  if (tid == 0) { bbase[NB] = total; offs[N2] = total; }
}

// ---- 5c. bin edges into 256-node buckets (counting-sort per 4096-edge chunk)
__global__ void __launch_bounds__(256) k_bin(
    const int* __restrict__ ei1, const int* __restrict__ et1,
    const int* __restrict__ ei2, const int* __restrict__ et2,
    int* __restrict__ bcur, uint2* __restrict__ staged, int N, int E, int NB) {
  __shared__ int hist[512];
  __shared__ int basev[512];
  __shared__ int runstart[512];
  __shared__ unsigned sta[4096 * 2];  // 32 KB staging (dstg, srcet)
  int tid = threadIdx.x;
  int E2 = 2 * E;
  int e0 = blockIdx.x * 4096;
  int cnt2 = min(4096, E2 - e0);
  for (int i = tid; i < 512; i += 256) hist[i] = 0;
  __syncthreads();
  int dstg[16], srcet[16], rank[16];
#pragma unroll
  for (int j = 0; j < 16; ++j) {
    int e = e0 + j * 256 + tid;
    dstg[j] = -1;
    if (e < E2) {
      int g = e >= E;
      int el = e - (g ? E : 0);
      const int* ei = g ? ei2 : ei1;
      int s = ei[el], d = ei[E + el];
      int etv = (g ? et2 : et1)[el];
      dstg[j] = g * N + d;
      srcet[j] = (s << 3) | etv;
      rank[j] = atomicAdd(&hist[dstg[j] >> 8], 1);
    }
  }
  __syncthreads();
  basev[tid] = hist[tid];
  basev[tid + 256] = hist[tid + 256];
  __syncthreads();
  for (int off = 1; off < 512; off <<= 1) {
    int i0 = tid, i1 = tid + 256;
    int v0 = (i0 >= off) ? basev[i0 - off] : 0;
    int v1 = (i1 >= off) ? basev[i1 - off] : 0;
    __syncthreads();
    basev[i0] += v0; basev[i1] += v1;
    __syncthreads();
  }
  for (int i = tid; i < NB; i += 256)
    if (hist[i] > 0) runstart[i] = atomicAdd(&bcur[i], hist[i]);
  __syncthreads();
#pragma unroll
  for (int j = 0; j < 16; ++j)
    if (dstg[j] >= 0) {
      int b = dstg[j] >> 8;
      int slot = basev[b] - hist[b] + rank[j];
      sta[slot * 2] = (unsigned)dstg[j];
      sta[slot * 2 + 1] = (unsigned)srcet[j];
    }
  __syncthreads();
  for (int i = tid; i < cnt2; i += 256) {
    unsigned dg = sta[i * 2], se = sta[i * 2 + 1];
    int b = (int)(dg >> 8);
    int dest = runstart[b] + (i - (basev[b] - hist[b]));
    staged[dest] = make_uint2(dg, se);
  }
}

// ---- 5d. per-bucket: node-level offs + final sorted csr ---------------------
__global__ void __launch_bounds__(256) k_scatter2(
    const uint2* __restrict__ staged, const int* __restrict__ bbase,
    int* __restrict__ offs, int* __restrict__ csr, int N2) {
  __shared__ int hist[256];
  __shared__ int sd[256];
  __shared__ int cur[256];
  int b = blockIdx.x, tid = threadIdx.x;
  int nb0 = b << 8;
  int nnode = min(256, N2 - nb0);
  int s0 = bbase[b], s1 = bbase[b + 1];
  hist[tid] = 0;
  __syncthreads();
  for (int i = s0 + tid; i < s1; i += 256)
    atomicAdd(&hist[(int)staged[i].x - nb0], 1);
  __syncthreads();
  int v = hist[tid];
  sd[tid] = v; __syncthreads();
  for (int off = 1; off < 256; off <<= 1) {
    int t = (tid >= off) ? sd[tid - off] : 0;
    __syncthreads();
    sd[tid] += t;
    __syncthreads();
  }
  int ex = sd[tid] - v;  // exclusive scan
  if (tid < nnode) offs[nb0 + tid] = s0 + ex;
  cur[tid] = ex;
  __syncthreads();
  for (int i = s0 + tid; i < s1; i += 256) {
    uint2 en = staged[i];
    int node = (int)en.x - nb0;
    int sl = atomicAdd(&cur[node], 1);
    csr[s0 + sl] = (int)en.y;
  }
}

// ---- 6a. xt[r][n][c] = x_n @ W_r, fused [sq|sk] = x @ [Wq|Wk] ---------------
// Operand swap (A=Wb/W^T, B=x frags), XOR-granule-swizzled single 16KB
// wave-private LDS staging (no barriers), gridDim.y=4 (2 relations/block).
__global__ void __launch_bounds__(256) k_gemm_xt(
    const float* __restrict__ x, const u16* __restrict__ Wb,
    const u16* __restrict__ Bqk, u16* __restrict__ xt,
    float* __restrict__ sq, float* __restrict__ sk,
    int N, int R, int node_base) {
  __shared__ u16 st[4][2048];  // 4 waves x 4KB (single buffer)
  int wave = threadIdx.x >> 6, lane = threadIdx.x & 63;
  int m0 = blockIdx.x * 64 + wave * 16;
  int rbase = blockIdx.y * 2;
  int q = lane >> 4, m16 = lane & 15;
  int node = m0 + m16;
  int srow = (node < N) ? node : N - 1;
  short8 bfrag[4];
#pragma unroll
  for (int kk = 0; kk < 4; ++kk) {
    const float* ap = x + (size_t)srow * 128 + kk * 32 + q * 8;
    float4v f0 = *(const float4v*)ap;
    float4v f1 = *(const float4v*)(ap + 4);
    short8 a;
    a[0] = (short)f2bf(f0.x); a[1] = (short)f2bf(f0.y);
    a[2] = (short)f2bf(f0.z); a[3] = (short)f2bf(f0.w);
    a[4] = (short)f2bf(f1.x); a[5] = (short)f2bf(f1.y);
    a[6] = (short)f2bf(f1.z); a[7] = (short)f2bf(f1.w);
    bfrag[kk] = a;
  }
  if (blockIdx.y == 0) {
    floatx4 accq = (floatx4){0.f, 0.f, 0.f, 0.f};
#pragma unroll
    for (int kk = 0; kk < 4; ++kk) {
      short8 aq = *(const short8*)(Bqk + (size_t)kk * 512 + lane * 8);
      accq = __builtin_amdgcn_mfma_f32_16x16x32_bf16(aq, bfrag[kk], accq, 0, 0, 0);
    }
    if (node < N) {
      float* dst = (q < 2 ? sq : sk) + (size_t)(node_base + node) * 8 + (q & 1) * 4;
      *(float4v*)dst = (float4v){accq[0], accq[1], accq[2], accq[3]};
    }
  }
  u16* s = st[wave];
#pragma unroll
  for (int rr = 0; rr < 2; ++rr) {
    int r = rbase + rr;
    floatx4 acc[8];
#pragma unroll
    for (int nt = 0; nt < 8; ++nt) acc[nt] = (floatx4){0.f, 0.f, 0.f, 0.f};
#pragma unroll
    for (int kk = 0; kk < 4; ++kk) {
      const u16* wbp = Wb + ((size_t)((r * 4 + kk) * 8) * 64 + lane) * 8;
#pragma unroll
      for (int nt = 0; nt < 8; ++nt) {
        short8 a = *(const short8*)(wbp + nt * 512);
        acc[nt] = __builtin_amdgcn_mfma_f32_16x16x32_bf16(a, bfrag[kk], acc[nt], 0, 0, 0);
      }
    }
    // swizzled transpose write: row m16, granule c16 = 2nt+(q>>1), half q&1
#pragma unroll
    for (int nt = 0; nt < 8; ++nt) {
      union { u16 h[4]; unsigned long long u; } pk;
      pk.h[0] = f2bf(acc[nt][0]); pk.h[1] = f2bf(acc[nt][1]);
      pk.h[2] = f2bf(acc[nt][2]); pk.h[3] = f2bf(acc[nt][3]);
      int c16 = 2 * nt + (q >> 1);
      *(unsigned long long*)(s + (((m16 << 4) + (c16 ^ m16)) << 3) + ((q & 1) << 2)) = pk.u;
    }
    // swizzled read: row rl = it*4+q, granule m16 -> 16B chunk m16 of row rl
#pragma unroll
    for (int it = 0; it < 4; ++it) {
      int rl = it * 4 + q;
      int gm = m0 + rl;
      if (gm < N) {
        uint4v vv = *(const uint4v*)(s + (((rl << 4) + (m16 ^ rl)) << 3));
        *(uint4v*)(xt + ((size_t)r * N + gm) * 128 + m16 * 8) = vv;
      }
    }
  }
}

// ---- 6b. per-dst softmax + gather: one wave per node ------------------------
__global__ void __launch_bounds__(256) k_aggregate(
    const int* __restrict__ csr, const int* __restrict__ offs,
    const float* __restrict__ sq, const float* __restrict__ sk,
    const u16* __restrict__ xt, const float* __restrict__ bias,
    float* __restrict__ out, int N, int node_base) {
  int nl = blockIdx.x * 4 + (threadIdx.x >> 6);
  int lane = threadIdx.x & 63;
  if (nl >= N) return;
  int node = node_base + nl;
  int start = offs[node], end = offs[node + 1];
  const float* sqn = sq + (size_t)node * 8;

  float al[8]; int pl[8];
  float m = -INFINITY;
  {
    int c = 0;
    for (int i = start + lane; i < end; i += 64, ++c) {
      int p = csr[i]; int s = p >> 3, e = p & 7;
      float a = sqn[e] + sk[(size_t)(node_base + s) * 8 + e];
      a = (a > 0.f) ? a : 0.2f * a;
      if (c < 8) { al[c] = a; pl[c] = p; }
      m = fmaxf(m, a);
    }
  }
#pragma unroll
  for (int off = 32; off; off >>= 1) m = fmaxf(m, __shfl_xor(m, off));

  float ssum = 0.f;
  {
    int c = 0;
    for (int i = start + lane; i < end; i += 64, ++c) {
      float a;
      if (c < 8) a = al[c];
      else {
        int p = csr[i]; int s = p >> 3, e = p & 7;
        a = sqn[e] + sk[(size_t)(node_base + s) * 8 + e];
        a = (a > 0.f) ? a : 0.2f * a;
      }
      ssum += __expf(a - m);
    }
  }
#pragma unroll
  for (int off = 32; off; off >>= 1) ssum += __shfl_xor(ssum, off);
  float inv = 1.f / (ssum + 1e-16f);

  float acc0 = 0.f, acc1 = 0.f;
  const char* xtb = (const char*)xt;
  int c = 0;
  for (int base = start; base < end; base += 64, ++c) {
    int cnt = min(64, end - base);
    float w = 0.f; int b = 0;
    {
      int i = base + lane;
      if (i < end) {
        int p; float a;
        if (c < 8) { p = pl[c]; a = al[c]; }
        else {
          p = csr[i]; int s = p >> 3, e = p & 7;
          a = sqn[e] + sk[(size_t)(node_base + s) * 8 + e];
          a = (a > 0.f) ? a : 0.2f * a;
        }
        w = __expf(a - m) * inv;
        b = ((p & 7) * N + (p >> 3)) << 8;  // xt row base in BYTES
      }
    }
    int j = 0;
    for (; j + 3 < cnt; j += 4) {
      float w0 = __shfl(w, j), w1 = __shfl(w, j + 1),
            w2 = __shfl(w, j + 2), w3 = __shfl(w, j + 3);
      int b0 = __shfl(b, j), b1 = __shfl(b, j + 1),
          b2 = __shfl(b, j + 2), b3 = __shfl(b, j + 3);
      unsigned v0 = *(const unsigned*)(xtb + b0 + lane * 4);
      unsigned v1 = *(const unsigned*)(xtb + b1 + lane * 4);
      unsigned v2 = *(const unsigned*)(xtb + b2 + lane * 4);
      unsigned v3 = *(const unsigned*)(xtb + b3 + lane * 4);
      acc0 += w0 * bflo(v0); acc1 += w0 * bfhi(v0);
      acc0 += w1 * bflo(v1); acc1 += w1 * bfhi(v1);
      acc0 += w2 * bflo(v2); acc1 += w2 * bfhi(v2);
      acc0 += w3 * bflo(v3); acc1 += w3 * bfhi(v3);
    }
    for (; j < cnt; ++j) {
      float w0 = __shfl(w, j);
      int b0 = __shfl(b, j);
      unsigned v0 = *(const unsigned*)(xtb + b0 + lane * 4);
      acc0 += w0 * bflo(v0); acc1 += w0 * bfhi(v0);
    }
  }
  float o0 = fmaxf(acc0 + bias[lane * 2], 0.f);
  float o1 = fmaxf(acc1 + bias[lane * 2 + 1], 0.f);
  union { float f[2]; unsigned long long u; } pk;
  pk.f[0] = o0; pk.f[1] = o1;
  __builtin_nontemporal_store(pk.u,
      (unsigned long long*)(out + (size_t)nl * 128 + lane * 2));
}

// -----------------------------------------------------------------------------
extern "C" void kernel_launch(void* const* d_in, const int* in_sizes, int n_in,
                              void* d_out, int out_size, void* d_ws, size_t ws_size,
                              hipStream_t stream) {
  const float* x1 = (const float*)d_in[0];
  const int* ei1 = (const int*)d_in[1];
  const int* et1 = (const int*)d_in[2];
  const float* x2 = (const float*)d_in[3];
  const int* ei2 = (const int*)d_in[4];
  const int* et2 = (const int*)d_in[5];
  const float* W1 = (const float*)d_in[6];
  const float* q1 = (const float*)d_in[7];
  const float* k1 = (const float*)d_in[8];
  const float* b1 = (const float*)d_in[9];
  const float* W2 = (const float*)d_in[10];
  const float* q2 = (const float*)d_in[11];
  const float* k2 = (const float*)d_in[12];
  const float* b2 = (const float*)d_in[13];

  const int N = in_sizes[0] / 128;
  const int E = in_sizes[1] / 2;
  const int R = in_sizes[6] / (128 * 128);
  const int KK = R * 4;
  const int N2 = 2 * N;
  const int NB = (N2 + 255) >> 8;           // 256-node buckets (<=512)

  size_t off = 0;
  char* w = (char*)d_ws;
  auto carve = [&](size_t bytes) -> void* {
    void* p = w + off;
    off += (bytes + 255) & ~(size_t)255;
    return p;
  };
  u16* xt = (u16*)carve((size_t)R * N * 128 * 2);       // per-graph, reused
  uint2* staged = (uint2*)xt;                           // ALIAS: dead before gemm_xt
  u16* Wb = (u16*)carve((size_t)2 * KK * 4096 * 2);
  u16* Bqk = (u16*)carve((size_t)2 * 4 * 64 * 8 * 2);
  float* Wq = (float*)carve((size_t)2 * R * 128 * 4);
  float* Wk = (float*)carve((size_t)2 * R * 128 * 4);
  float* sq = (float*)carve((size_t)N2 * 8 * 4);
  float* sk = (float*)carve((size_t)N2 * 8 * 4);
  int* offs = (int*)carve((size_t)(N2 + 1) * 4);
  int* gcnt = (int*)carve(512 * 4);
  int* bbase = (int*)carve(520 * 4);
  int* bcur = (int*)carve(512 * 4);
  int* csr = (int*)carve((size_t)2 * E * 4);
  if (off > ws_size) return;

  const int nbin = (2 * E + 4095) / 4096;

  hipMemsetAsync(gcnt, 0, 512 * 4, stream);
  k_prep_wb<<<dim3((KK * 512 + 255) / 256, 2), dim3(256), 0, stream>>>(W1, W2, Wb, KK);
  k_prep_wqk<<<dim3((2 * R * 128 * 64 + 255) / 256), dim3(256), 0, stream>>>(
      W1, q1, k1, W2, q2, k2, Wq, Wk, R * 128);
  k_prep_bqk<<<dim3(1), dim3(256), 0, stream>>>(Wq, Wk, Bqk, R);
  k_count<<<dim3(nbin), dim3(256), 0, stream>>>(ei1 + E, ei2 + E, gcnt, N, E, NB);
  k_bucket_scan<<<dim3(1), dim3(256), 0, stream>>>(gcnt, bbase, bcur, offs, NB, 2 * E, N2);
  k_bin<<<dim3(nbin), dim3(256), 0, stream>>>(ei1, et1, ei2, et2, bcur, staged, N, E, NB);
  k_scatter2<<<dim3(NB), dim3(256), 0, stream>>>(staged, bbase, offs, csr, N2);

  for (int g = 0; g < 2; ++g) {
    const float* x = g ? x2 : x1;
    const float* bv = g ? b2 : b1;
    float* outp = (float*)d_out + (size_t)g * N * 128;
    k_gemm_xt<<<dim3((N + 63) / 64, 4), dim3(256), 0, stream>>>(
        x, Wb + (size_t)g * KK * 4096, Bqk + (size_t)g * 2048, xt,
        sq, sk, N, R, g * N);
    k_aggregate<<<dim3((N + 3) / 4), dim3(256), 0, stream>>>(
        csr, offs, sq, sk, xt, bv, outp, N, g * N);
  }
}